// Round 9
// baseline (1077.099 us; speedup 1.0000x reference)
//
#include <hip/hip_runtime.h>
#include <hip/hip_bf16.h>

typedef unsigned int u32;
typedef unsigned short u16;

typedef _Float16 half2_t __attribute__((ext_vector_type(2)));
union H2U { u32 u; half2_t h; };

#if defined(__has_builtin)
#if __has_builtin(__builtin_amdgcn_fdot2)
#define HAS_FDOT2 1
#endif
#endif

__device__ __forceinline__ float bf2f(u32 u) {
  union { u32 i; float f; } v; v.i = u << 16; return v.f;
}
__device__ __forceinline__ float sigf(float x) {
  return 1.0f / (1.0f + __expf(-x));
}
__device__ __forceinline__ float tanhfast(float x) {
  return 2.0f / (1.0f + __expf(-2.0f * x)) - 1.0f;
}
__device__ __forceinline__ u16 f2bf(float f) {
  u32 u = __float_as_uint(f);
  u += 0x7fffu + ((u >> 16) & 1u);
  return (u16)(u >> 16);
}
__device__ __forceinline__ float dot2acc(u32 wu, u32 hu, float acc) {
  H2U w, h; w.u = wu; h.u = hu;
#ifdef HAS_FDOT2
  return __builtin_amdgcn_fdot2(w.h, h.h, acc, false);
#else
  acc = fmaf((float)w.h.x, (float)h.h.x, acc);
  return fmaf((float)w.h.y, (float)h.h.y, acc);
#endif
}

// ---- runtime dtype detection (bf16 vs fp32 inputs) ----
__global__ void k_detect(const u32* __restrict__ w, int* __restrict__ flag) {
  __shared__ int cnt;
  if (threadIdx.x == 0) cnt = 0;
  __syncthreads();
  int c = 0;
  for (int i = threadIdx.x; i < 8192; i += 256) {
    const u32 lo = w[i] & 0xffffu;
    const u32 e = (lo >> 7) & 0xffu;
    c += (e >= 100u && e <= 140u) ? 1 : 0;
  }
  atomicAdd(&cnt, c);
  __syncthreads();
  if (threadIdx.x == 0) *flag = (cnt > 4915) ? 1 : 0;
}

struct Job { const void* s; float* d; int n; };
struct Jobs { Job j[30]; };

__global__ void k_cvt_all(Jobs J, const int* __restrict__ flag) {
  const Job jb = J.j[blockIdx.y];
  const int isbf = *flag;
  for (int i = blockIdx.x * 256 + threadIdx.x; i < jb.n; i += 32 * 256) {
    jb.d[i] = isbf ? bf2f(((const u16*)jb.s)[i]) : ((const float*)jb.s)[i];
  }
}

// 4 bias-broadcast inits in one dispatch
struct IJobs { const float* b[4]; float* d[4]; int n[4]; int mask[4]; };
__global__ void k_init4(IJobs I) {
  const int j = blockIdx.y;
  const float* bb = I.b[j];
  float* dd = I.d[j];
  const int n = I.n[j], mask = I.mask[j];
  for (int i = blockIdx.x * 256 + threadIdx.x; i < n; i += gridDim.x * 256)
    dd[i] = bb[i & mask];
}

// Pack staged fp32 recurrent weights into the gate-in-wave per-thread f16-pair
// layout consumed by k_rec: thread tid reads dst[tid*64 + c] =
// pack(W[row][2c], W[row][2c+1]), row = (lane>>4)*128 + (tid>>6)*16 + (lane&15),
// lane = tid&63.  Optional second source s2 -> element-wise sum (dec Wih+Whh).
struct PJobs { const float* s[7]; const float* s2[7]; u32* d[7]; };
__global__ void k_pack(PJobs P) {
  const float* src = P.s[blockIdx.y];
  const float* src2 = P.s2[blockIdx.y];
  u32* dst = P.d[blockIdx.y];
  const int i = blockIdx.x * 256 + threadIdx.x;   // 0..32767
  const int tid = i >> 6, c = i & 63;
  const int lane = tid & 63;
  const int row = (lane >> 4) * 128 + (tid >> 6) * 16 + (lane & 15);
  float v0 = src[row * 128 + 2 * c];
  float v1 = src[row * 128 + 2 * c + 1];
  if (src2) { v0 += src2[row * 128 + 2 * c]; v1 += src2[row * 128 + 2 * c + 1]; }
  H2U v;
  v.h.x = (_Float16)v0;
  v.h.y = (_Float16)v1;
  dst[i] = v.u;
}

// C[M,N] (+)= A[M,K] @ W[N,K]^T (+bias). 32-wide K staging, 16 B/lane loads.
__launch_bounds__(256)
__global__ void k_gemm(const float* __restrict__ A, int lda,
                       const void* __restrict__ Wv, int ldw,
                       const float* __restrict__ bias,
                       float* __restrict__ C, int ldc,
                       int K, int actA, int atom, int wfollow,
                       const int* __restrict__ dflag)
{
  __shared__ float As[32][65];
  __shared__ float Ws[32][65];
  const int isbf = wfollow ? *dflag : 0;
  const int tid = threadIdx.x;
  const int tx = tid & 15, ty = tid >> 4;
  const int m0 = blockIdx.x * 64, n0 = blockIdx.y * 64;
  const int kc = K / gridDim.z;
  const int k0 = blockIdx.z * kc;
  const int lr = tid >> 2;
  const int lk = (tid & 3) << 3;
  float acc[4][4] = {{0.f}};
  const float* Ap   = A + (size_t)(m0 + lr) * lda + k0 + lk;
  const u16*   Wp16 = (const u16*)Wv   + (size_t)(n0 + lr) * ldw + k0 + lk;
  const float* Wp32 = (const float*)Wv + (size_t)(n0 + lr) * ldw + k0 + lk;
  for (int kk = 0; kk < kc; kk += 32) {
    float4 av0 = *(const float4*)(Ap + kk);
    float4 av1 = *(const float4*)(Ap + kk + 4);
    float wv[8];
    if (isbf) {
      const uint4 wu = *(const uint4*)(Wp16 + kk);
      wv[0]=bf2f(wu.x & 0xffffu); wv[1]=bf2f(wu.x >> 16);
      wv[2]=bf2f(wu.y & 0xffffu); wv[3]=bf2f(wu.y >> 16);
      wv[4]=bf2f(wu.z & 0xffffu); wv[5]=bf2f(wu.z >> 16);
      wv[6]=bf2f(wu.w & 0xffffu); wv[7]=bf2f(wu.w >> 16);
    } else {
      const float4 w0 = *(const float4*)(Wp32 + kk);
      const float4 w1 = *(const float4*)(Wp32 + kk + 4);
      wv[0]=w0.x; wv[1]=w0.y; wv[2]=w0.z; wv[3]=w0.w;
      wv[4]=w1.x; wv[5]=w1.y; wv[6]=w1.z; wv[7]=w1.w;
    }
    if (actA) {
      av0.x = tanhfast(av0.x); av0.y = tanhfast(av0.y);
      av0.z = tanhfast(av0.z); av0.w = tanhfast(av0.w);
      av1.x = tanhfast(av1.x); av1.y = tanhfast(av1.y);
      av1.z = tanhfast(av1.z); av1.w = tanhfast(av1.w);
    }
    __syncthreads();
    As[lk+0][lr] = av0.x; As[lk+1][lr] = av0.y;
    As[lk+2][lr] = av0.z; As[lk+3][lr] = av0.w;
    As[lk+4][lr] = av1.x; As[lk+5][lr] = av1.y;
    As[lk+6][lr] = av1.z; As[lk+7][lr] = av1.w;
    #pragma unroll
    for (int q = 0; q < 8; ++q) Ws[lk+q][lr] = wv[q];
    __syncthreads();
    #pragma unroll
    for (int k = 0; k < 32; ++k) {
      float a[4], w[4];
      #pragma unroll
      for (int i = 0; i < 4; ++i) a[i] = As[k][ty + 16*i];
      #pragma unroll
      for (int j = 0; j < 4; ++j) w[j] = Ws[k][tx + 16*j];
      #pragma unroll
      for (int i = 0; i < 4; ++i)
        #pragma unroll
        for (int j = 0; j < 4; ++j)
          acc[i][j] = fmaf(a[i], w[j], acc[i][j]);
    }
  }
  #pragma unroll
  for (int i = 0; i < 4; ++i) {
    const int m = m0 + ty + 16*i;
    #pragma unroll
    for (int j = 0; j < 4; ++j) {
      const int n = n0 + tx + 16*j;
      if (atom) atomicAdd(&C[(size_t)m*ldc + n], acc[i][j]);
      else {
        const float bv = bias ? bias[n] : 0.0f;
        C[(size_t)m*ldc + n] = acc[i][j] + bv;
      }
    }
  }
}

// Recurrence, 2 batch elements per block (amortizes the per-step latency chain,
// which rounds 6-8 proved invariant ~67us regardless of memory strategy).
// Gate-in-wave layout: lane = gate*16 + (r&15); wave w owns rows 16w..16w+15
// for ALL 4 gates; each thread computes full-K (64 dot2/elem, NO reduce).
// Gate values collected with 3 one-deep shfl_xor (vs 8 two-deep before).
// h in f16 pairs (unchanged numerics vs round 8). 1 barrier/step.
__launch_bounds__(512)
__attribute__((amdgpu_waves_per_eu(2, 2)))
__global__ void k_rec(const float* __restrict__ Zf, const float* __restrict__ Zb,
                      const u32* __restrict__ Wf, const u32* __restrict__ Wb,
                      float* __restrict__ HS, int hstride, int offF, int offB,
                      const float* __restrict__ h0, const float* __restrict__ c0,
                      int zmode, int zld, float* __restrict__ Cout, int nb)
{
  const int dir = (blockIdx.x >= nb) ? 1 : 0;
  const int b0 = (blockIdx.x - dir * nb) * 2;
  const float* Z = dir ? Zb : Zf;
  const u32* Wg = dir ? Wb : Wf;
  const int off = dir ? offB : offF;
  const int tid = threadIdx.x;
  const int lane = tid & 63;
  const int g = lane >> 4;
  const int rl = lane & 15;
  const int r = (tid >> 6) * 16 + rl;     // 0..127
  const int row = g * 128 + r;            // 0..511

  __shared__ __align__(16) u32 hbuf[2][2][64];   // f16 h pairs, dbuf x 2 elems
  __shared__ float hist[64][2][128];             // 64 KB h history for bulk flush

  u32 wp[64];
  {
    const uint4* wr = (const uint4*)(Wg + (size_t)tid * 64);
    #pragma unroll
    for (int q = 0; q < 16; ++q) {
      const uint4 u = wr[q];
      wp[q*4+0]=u.x; wp[q*4+1]=u.y; wp[q*4+2]=u.z; wp[q*4+3]=u.w;
    }
  }
  #pragma unroll
  for (int q = 0; q < 64; ++q)
    asm volatile("" : "+v"(wp[q]));

  float creg0 = 0.0f, creg1 = 0.0f;
  if (c0) {
    creg0 = c0[(size_t)(b0+0)*128 + r];
    creg1 = c0[(size_t)(b0+1)*128 + r];
  }
  if (tid < 128) {
    const int e = tid >> 6, m = tid & 63;
    H2U v;
    if (h0) {
      v.h.x = (_Float16)h0[(size_t)(b0+e)*128 + 2*m];
      v.h.y = (_Float16)h0[(size_t)(b0+e)*128 + 2*m + 1];
    } else {
      v.h.x = (_Float16)0.f; v.h.y = (_Float16)0.f;
    }
    hbuf[0][e][m] = v.u;
  }

  float zcst = 0.0f;
  float zcur0 = 0.0f, zcur1 = 0.0f;
  if (zmode) {
    zcst = Z[row];
  } else {
    const int s0 = dir ? 63 : 0;
    zcur0 = Z[((size_t)s0*64 + b0 + 0)*zld + row];
    zcur1 = Z[((size_t)s0*64 + b0 + 1)*zld + row];
  }
  __syncthreads();

  for (int t = 0; t < 64; ++t) {
    // prefetch next step's Z (in flight across the whole step)
    float znx0 = 0.f, znx1 = 0.f;
    if (!zmode && t < 63) {
      const int s2 = dir ? (62 - t) : (t + 1);
      znx0 = Z[((size_t)s2*64 + b0 + 0)*zld + row];
      znx1 = Z[((size_t)s2*64 + b0 + 1)*zld + row];
    }
    // full-K dot for this thread's gate row, both elems (broadcast LDS reads)
    float a00 = 0.f, a01 = 0.f, a10 = 0.f, a11 = 0.f;
    {
      const uint4* hp0 = (const uint4*)&hbuf[t & 1][0][0];
      const uint4* hp1 = (const uint4*)&hbuf[t & 1][1][0];
      #pragma unroll
      for (int c = 0; c < 16; ++c) {
        const uint4 x0 = hp0[c];
        const uint4 x1 = hp1[c];
        a00 = dot2acc(wp[c*4+0], x0.x, a00);
        a01 = dot2acc(wp[c*4+1], x0.y, a01);
        a00 = dot2acc(wp[c*4+2], x0.z, a00);
        a01 = dot2acc(wp[c*4+3], x0.w, a01);
        a10 = dot2acc(wp[c*4+0], x1.x, a10);
        a11 = dot2acc(wp[c*4+1], x1.y, a11);
        a10 = dot2acc(wp[c*4+2], x1.z, a10);
        a11 = dot2acc(wp[c*4+3], x1.w, a11);
      }
    }
    const float z0 = a00 + a01 + (zmode ? zcst : zcur0);
    const float z1 = a10 + a11 + (zmode ? zcst : zcur1);

    // collect the 4 gate values of row r (one-deep shuffles + selects)
    float hh0, hh1;
    {
      const float b1v = __shfl_xor(z0, 16, 64);
      const float c1v = __shfl_xor(z0, 32, 64);
      const float d1v = __shfl_xor(z0, 48, 64);
      const float zi = (g==0)?z0 : (g==1)?b1v : (g==2)?c1v : d1v;
      const float zf = (g==1)?z0 : (g==0)?b1v : (g==3)?c1v : d1v;
      const float zg = (g==2)?z0 : (g==3)?b1v : (g==0)?c1v : d1v;
      const float zo = (g==3)?z0 : (g==2)?b1v : (g==1)?c1v : d1v;
      const float cc = sigf(zf) * creg0 + sigf(zi) * tanhfast(zg);
      hh0 = sigf(zo) * tanhfast(cc);
      creg0 = cc;
    }
    {
      const float b1v = __shfl_xor(z1, 16, 64);
      const float c1v = __shfl_xor(z1, 32, 64);
      const float d1v = __shfl_xor(z1, 48, 64);
      const float zi = (g==0)?z1 : (g==1)?b1v : (g==2)?c1v : d1v;
      const float zf = (g==1)?z1 : (g==0)?b1v : (g==3)?c1v : d1v;
      const float zg = (g==2)?z1 : (g==3)?b1v : (g==0)?c1v : d1v;
      const float zo = (g==3)?z1 : (g==2)?b1v : (g==1)?c1v : d1v;
      const float cc = sigf(zf) * creg1 + sigf(zi) * tanhfast(zg);
      hh1 = sigf(zo) * tanhfast(cc);
      creg1 = cc;
    }
    // neighbor h for f16-pair packing (lane rl+1, same gate)
    const float hn0 = __shfl_down(hh0, 1, 64);
    const float hn1 = __shfl_down(hh1, 1, 64);
    if (g == 0) {
      hist[t][0][r] = hh0;
      hist[t][1][r] = hh1;
      if (!(rl & 1)) {
        H2U v0; v0.h.x = (_Float16)hh0; v0.h.y = (_Float16)hn0;
        H2U v1; v1.h.x = (_Float16)hh1; v1.h.y = (_Float16)hn1;
        hbuf[(t+1) & 1][0][r >> 1] = v0.u;
        hbuf[(t+1) & 1][1][r >> 1] = v1.u;
      }
    }
    __syncthreads();
    zcur0 = znx0; zcur1 = znx1;
  }

  // bulk flush h history (coalesced within rows)
  for (int i = tid; i < 2*64*128; i += 512) {
    const int e = i >> 13;
    const int rem = i & 8191;
    const int t = rem >> 7, k = rem & 127;
    const int s = dir ? (63 - t) : t;
    HS[((size_t)s*64 + b0 + e)*hstride + off + k] = hist[t][e][k];
  }
  if (Cout != nullptr && g == 0) {
    Cout[(size_t)(b0+0)*128 + r] = creg0;
    Cout[(size_t)(b0+1)*128 + r] = creg1;
  }
}

// Attention, fully parallel over (b, t-slice).
#define TS 132
__launch_bounds__(256, 1)
__global__ void k_att(const float* __restrict__ enco, const float* __restrict__ encp,
                      const float* __restrict__ Hdec, const float* __restrict__ Hproj,
                      const float* __restrict__ attw, float* __restrict__ flat)
{
  const int b = blockIdx.x;
  const int t0 = blockIdx.y * 16;
  const int tid = threadIdx.x;
  __shared__ __align__(16) float ep[64*TS];
  __shared__ __align__(16) float en[64*TS];
  __shared__ __align__(16) float hp[16*TS];
  __shared__ float S[64*17];
  __shared__ float aw[64*17];
  __shared__ __align__(16) float awt[128];

  for (int i = tid; i < 8192; i += 256) {
    const int s = i >> 7, k = i & 127;
    const size_t g = ((size_t)s*64 + b)*128 + k;
    ep[s*TS + k] = encp[g];
    en[s*TS + k] = enco[g];
  }
  for (int i = tid; i < 2048; i += 256) {
    const int t = i >> 7, k = i & 127;
    const size_t g = ((size_t)(t0 + t)*64 + b)*128 + k;
    hp[t*TS + k] = Hproj[g];
    flat[(size_t)b*16384 + (t0 + t)*256 + k] = Hdec[g];
  }
  if (tid < 128) awt[tid] = attw[tid];
  __syncthreads();

  {
    const int t = tid & 15, sg = tid >> 4;
    #pragma unroll
    for (int i = 0; i < 4; ++i) {
      const int s = sg*4 + i;
      float acc = 0.f;
      #pragma unroll 8
      for (int k = 0; k < 128; k += 4) {
        const float4 h4 = *(const float4*)&hp[t*TS + k];
        const float4 e4 = *(const float4*)&ep[s*TS + k];
        const float4 w4 = *(const float4*)&awt[k];
        acc = fmaf(w4.x, tanhfast(h4.x + e4.x), acc);
        acc = fmaf(w4.y, tanhfast(h4.y + e4.y), acc);
        acc = fmaf(w4.z, tanhfast(h4.z + e4.z), acc);
        acc = fmaf(w4.w, tanhfast(h4.w + e4.w), acc);
      }
      S[s*17 + t] = acc;
    }
  }
  __syncthreads();
  if (tid < 16) {
    const int t = tid;
    float m = -1e30f;
    for (int s = 0; s < 64; ++s) m = fmaxf(m, S[s*17 + t]);
    float sum = 0.f;
    for (int s = 0; s < 64; ++s) {
      const float e = __expf(S[s*17 + t] - m);
      aw[s*17 + t] = e;
      sum += e;
    }
    const float inv = 1.0f / sum;
    for (int s = 0; s < 64; ++s) aw[s*17 + t] *= inv;
  }
  __syncthreads();
  {
    const int t = tid >> 4, kg = tid & 15;
    float c0a[8] = {0,0,0,0,0,0,0,0};
    for (int s = 0; s < 64; ++s) {
      const float a = aw[s*17 + t];
      const float4 e0 = *(const float4*)&en[s*TS + kg*8];
      const float4 e1 = *(const float4*)&en[s*TS + kg*8 + 4];
      c0a[0] = fmaf(a, e0.x, c0a[0]);
      c0a[1] = fmaf(a, e0.y, c0a[1]);
      c0a[2] = fmaf(a, e0.z, c0a[2]);
      c0a[3] = fmaf(a, e0.w, c0a[3]);
      c0a[4] = fmaf(a, e1.x, c0a[4]);
      c0a[5] = fmaf(a, e1.y, c0a[5]);
      c0a[6] = fmaf(a, e1.z, c0a[6]);
      c0a[7] = fmaf(a, e1.w, c0a[7]);
    }
    float4 o0 = {c0a[0], c0a[1], c0a[2], c0a[3]};
    float4 o1 = {c0a[4], c0a[5], c0a[6], c0a[7]};
    float* dst = &flat[(size_t)b*16384 + (t0 + t)*256 + 128 + kg*8];
    *(float4*)dst = o0;
    *(float4*)(dst + 4) = o1;
  }
}

__global__ void k_head(const float* __restrict__ a4, const float* __restrict__ outW,
                       const float* __restrict__ outb, void* __restrict__ out,
                       const int* __restrict__ dflag)
{
  const int b = threadIdx.x;
  float acc = outb[0];
  #pragma unroll 8
  for (int k = 0; k < 128; ++k)
    acc = fmaf(outW[k], tanhfast(a4[b*128 + k]), acc);
  if (*dflag) ((u16*)out)[b] = f2bf(acc);
  else        ((float*)out)[b] = acc;
}

extern "C" void kernel_launch(void* const* d_in, const int* in_sizes, int n_in,
                              void* d_out, int out_size, void* d_ws, size_t ws_size,
                              hipStream_t stream)
{
  (void)in_sizes; (void)n_in; (void)out_size; (void)ws_size;

  float* p = (float*)d_ws;
  int*   flagp = (int*)p;    p += 64;
  float* x0    = p; p += 64*64*64;
  float* cl1Wih = p; p += 512*64;
  float* cl1Whh = p; p += 512*128;
  float* cl1b   = p; p += 512;
  float* c2Wih  = p; p += 1024*128;
  float* c2bias = p; p += 1024;
  float* c2fWhh = p; p += 512*128;
  float* c2bWhh = p; p += 512*128;
  float* c3Wih  = p; p += 1024*256;
  float* c3bias = p; p += 1024;
  float* c3fWhh = p; p += 512*128;
  float* c3bWhh = p; p += 512*128;
  float* ceWih  = p; p += 512*256;
  float* ceWhh  = p; p += 512*128;
  float* ceb    = p; p += 512;
  float* cdWih  = p; p += 512*128;
  float* cdWhh  = p; p += 512*128;
  float* cdb    = p; p += 512;
  float* cattW  = p; p += 128*128;
  float* cattw  = p; p += 128;
  float* cW1b   = p; p += 1024;
  float* cW2b   = p; p += 512;
  float* cW3b   = p; p += 256;
  float* cW4b   = p; p += 128;
  float* coW    = p; p += 128;
  float* cob    = p; p += 16;
  u32* wpL1 = (u32*)p; p += 32768;
  u32* wp2f = (u32*)p; p += 32768;
  u32* wp2b = (u32*)p; p += 32768;
  u32* wp3f = (u32*)p; p += 32768;
  u32* wp3b = (u32*)p; p += 32768;
  u32* wpE  = (u32*)p; p += 32768;
  u32* wpD  = (u32*)p; p += 32768;
  float* Zf   = p; p += 4096*512;
  float* Z2   = p; p += 4096*1024;
  float* h1   = p; p += 4096*128;
  float* x2   = p; p += 4096*256;
  float* x3   = p; p += 4096*256;
  float* enco = p; p += 4096*128;   // enco and Hdec contiguous (merged proj A)
  float* Hdec = p; p += 4096*128;
  float* encp = p; p += 4096*128;   // encp and Hprj contiguous (merged proj C)
  float* Hprj = p; p += 4096*128;
  float* ec   = p; p += 64*128;
  float* flat = p; p += 64*16384;
  float* a1   = p; p += 64*1024;
  float* a2   = p; p += 64*512;
  float* a3   = p; p += 64*256;
  float* a4   = p; p += 64*128;

  k_detect<<<1, 256, 0, stream>>>((const u32*)d_in[2], flagp);

  Jobs J;
  int nj = 0;
  auto add = [&](const void* s, float* d, int n) { J.j[nj].s = s; J.j[nj].d = d; J.j[nj].n = n; ++nj; };
  add(d_in[0],  x0,     64*64*64);
  add(d_in[1],  cl1Wih, 512*64);
  add(d_in[2],  cl1Whh, 512*128);
  add(d_in[3],  cl1b,   512);
  add(d_in[4],  c2Wih,            512*128);
  add(d_in[7],  c2Wih + 512*128,  512*128);
  add(d_in[6],  c2bias,       512);
  add(d_in[9],  c2bias + 512, 512);
  add(d_in[5],  c2fWhh, 512*128);
  add(d_in[8],  c2bWhh, 512*128);
  add(d_in[10], c3Wih,            512*256);
  add(d_in[13], c3Wih + 512*256,  512*256);
  add(d_in[12], c3bias,       512);
  add(d_in[15], c3bias + 512, 512);
  add(d_in[11], c3fWhh, 512*128);
  add(d_in[14], c3bWhh, 512*128);
  add(d_in[16], ceWih,  512*256);
  add(d_in[17], ceWhh,  512*128);
  add(d_in[18], ceb,    512);
  add(d_in[19], cdWih,  512*128);
  add(d_in[20], cdWhh,  512*128);
  add(d_in[21], cdb,    512);
  add(d_in[22], cattW,  128*128);
  add(d_in[23], cattw,  128);
  add(d_in[25], cW1b,   1024);
  add(d_in[27], cW2b,   512);
  add(d_in[29], cW3b,   256);
  add(d_in[31], cW4b,   128);
  add(d_in[32], coW,    128);
  add(d_in[33], cob,    1);
  k_cvt_all<<<dim3(32, nj), 256, 0, stream>>>(J, flagp);

  // pack all recurrent weight matrices into gate-in-wave f16-pair layout;
  // dec entry sums Wih+Whh in-pack (xin == h_prev in the reference recurrence)
  PJobs P;
  for (int i = 0; i < 7; ++i) P.s2[i] = nullptr;
  P.s[0] = cl1Whh; P.d[0] = wpL1;
  P.s[1] = c2fWhh; P.d[1] = wp2f;
  P.s[2] = c2bWhh; P.d[2] = wp2b;
  P.s[3] = c3fWhh; P.d[3] = wp3f;
  P.s[4] = c3bWhh; P.d[4] = wp3b;
  P.s[5] = ceWhh;  P.d[5] = wpE;
  P.s[6] = cdWih;  P.s2[6] = cdWhh; P.d[6] = wpD;
  k_pack<<<dim3(128, 7), 256, 0, stream>>>(P);

  // lstm1
  k_gemm<<<dim3(64,8,1), 256, 0, stream>>>(x0, 64, cl1Wih, 64, cl1b, Zf, 512, 64, 0, 0, 0, flagp);
  k_rec<<<32, 512, 0, stream>>>(Zf, Zf, wpL1, wpL1, h1, 128, 0, 0, nullptr, nullptr, 0, 512, nullptr, 32);

  // biLSTM 2 (f+b input GEMM merged: N=1024, shared A)
  k_gemm<<<dim3(64,16,1), 256, 0, stream>>>(h1, 128, c2Wih, 128, c2bias, Z2, 1024, 128, 0, 0, 0, flagp);
  k_rec<<<64, 512, 0, stream>>>(Z2, Z2 + 512, wp2f, wp2b, x2, 256, 0, 128, nullptr, nullptr, 0, 1024, nullptr, 32);

  // biLSTM 3 (merged)
  k_gemm<<<dim3(64,16,1), 256, 0, stream>>>(x2, 256, c3Wih, 256, c3bias, Z2, 1024, 256, 0, 0, 0, flagp);
  k_rec<<<64, 512, 0, stream>>>(Z2, Z2 + 512, wp3f, wp3b, x3, 256, 0, 128, nullptr, nullptr, 0, 1024, nullptr, 32);

  // encoder
  k_gemm<<<dim3(64,8,1), 256, 0, stream>>>(x3, 256, ceWih, 256, ceb, Zf, 512, 256, 0, 0, 0, flagp);
  k_rec<<<32, 512, 0, stream>>>(Zf, Zf, wpE, wpE, enco, 128, 0, 0, nullptr, nullptr, 0, 512, ec, 32);

  // decoder recurrence (attention-independent): h0 = enco[63], c0 = ec, Z = bias
  k_rec<<<32, 512, 0, stream>>>(cdb, cdb, wpD, wpD, Hdec, 128, 0, 0,
                                enco + (size_t)63*64*128, ec, 1, 512, nullptr, 32);

  // merged projection: [enco;Hdec] @ attW^T -> [encp;Hprj]  (M=8192)
  k_gemm<<<dim3(128,2,1), 256, 0, stream>>>(enco, 128, cattW, 128, nullptr, encp, 128, 128, 0, 0, 0, flagp);

  // attention (parallel over 64 b x 4 t-slices) -> flat [64, 16384]
  k_att<<<dim3(64,4), 256, 0, stream>>>(enco, encp, Hdec, Hprj, cattw, flat);

  // MLP: all bias-inits in one dispatch, then split-K atomic GEMMs
  IJobs I;
  I.b[0]=cW1b; I.d[0]=a1; I.n[0]=64*1024; I.mask[0]=1023;
  I.b[1]=cW2b; I.d[1]=a2; I.n[1]=64*512;  I.mask[1]=511;
  I.b[2]=cW3b; I.d[2]=a3; I.n[2]=64*256;  I.mask[2]=255;
  I.b[3]=cW4b; I.d[3]=a4; I.n[3]=64*128;  I.mask[3]=127;
  k_init4<<<dim3(64, 4), 256, 0, stream>>>(I);
  k_gemm<<<dim3(1,16,64), 256, 0, stream>>>(flat, 16384, d_in[24], 16384, nullptr, a1, 1024, 16384, 0, 1, 1, flagp);
  k_gemm<<<dim3(1,8,16), 256, 0, stream>>>(a1, 1024, d_in[26], 1024, nullptr, a2, 512, 1024, 1, 1, 1, flagp);
  k_gemm<<<dim3(1,4,8), 256, 0, stream>>>(a2, 512, d_in[28], 512, nullptr, a3, 256, 512, 1, 1, 1, flagp);
  k_gemm<<<dim3(1,2,4), 256, 0, stream>>>(a3, 256, d_in[30], 256, nullptr, a4, 128, 256, 1, 1, 1, flagp);

  k_head<<<1, 64, 0, stream>>>(a4, coW, cob, d_out, flagp);
}

// Round 10
// 691.888 us; speedup vs baseline: 1.5568x; 1.5568x over previous
//
#include <hip/hip_runtime.h>
#include <hip/hip_bf16.h>

typedef unsigned int u32;
typedef unsigned short u16;

typedef _Float16 half2_t __attribute__((ext_vector_type(2)));
union H2U { u32 u; half2_t h; };

#if defined(__has_builtin)
#if __has_builtin(__builtin_amdgcn_fdot2)
#define HAS_FDOT2 1
#endif
#if __has_builtin(__builtin_amdgcn_update_dpp)
#define HAS_DPP 1
#endif
#endif

__device__ __forceinline__ float bf2f(u32 u) {
  union { u32 i; float f; } v; v.i = u << 16; return v.f;
}
__device__ __forceinline__ float sigf(float x) {
  return 1.0f / (1.0f + __expf(-x));
}
__device__ __forceinline__ float tanhfast(float x) {
  return 2.0f / (1.0f + __expf(-2.0f * x)) - 1.0f;
}
__device__ __forceinline__ u16 f2bf(float f) {
  u32 u = __float_as_uint(f);
  u += 0x7fffu + ((u >> 16) & 1u);
  return (u16)(u >> 16);
}
__device__ __forceinline__ float dot2acc(u32 wu, u32 hu, float acc) {
  H2U w, h; w.u = wu; h.u = hu;
#ifdef HAS_FDOT2
  return __builtin_amdgcn_fdot2(w.h, h.h, acc, false);
#else
  acc = fmaf((float)w.h.x, (float)h.h.x, acc);
  return fmaf((float)w.h.y, (float)h.h.y, acc);
#endif
}
// quad butterfly adds on the VALU via DPP (no DS-pipe shuffles):
// quad_perm[1,0,3,2] = 0xB1 (xor lane 1), quad_perm[2,3,0,1] = 0x4E (xor lane 2)
__device__ __forceinline__ float qadd_xor1(float x) {
#ifdef HAS_DPP
  int y = __builtin_amdgcn_update_dpp(0, __float_as_int(x), 0xB1, 0xF, 0xF, true);
  return x + __int_as_float(y);
#else
  return x + __shfl_xor(x, 1, 64);
#endif
}
__device__ __forceinline__ float qadd_xor2(float x) {
#ifdef HAS_DPP
  int y = __builtin_amdgcn_update_dpp(0, __float_as_int(x), 0x4E, 0xF, 0xF, true);
  return x + __int_as_float(y);
#else
  return x + __shfl_xor(x, 2, 64);
#endif
}

// ---- runtime dtype detection (bf16 vs fp32 inputs) ----
__global__ void k_detect(const u32* __restrict__ w, int* __restrict__ flag) {
  __shared__ int cnt;
  if (threadIdx.x == 0) cnt = 0;
  __syncthreads();
  int c = 0;
  for (int i = threadIdx.x; i < 8192; i += 256) {
    const u32 lo = w[i] & 0xffffu;
    const u32 e = (lo >> 7) & 0xffu;
    c += (e >= 100u && e <= 140u) ? 1 : 0;
  }
  atomicAdd(&cnt, c);
  __syncthreads();
  if (threadIdx.x == 0) *flag = (cnt > 4915) ? 1 : 0;
}

struct Job { const void* s; float* d; int n; };
struct Jobs { Job j[30]; };

__global__ void k_cvt_all(Jobs J, const int* __restrict__ flag) {
  const Job jb = J.j[blockIdx.y];
  const int isbf = *flag;
  for (int i = blockIdx.x * 256 + threadIdx.x; i < jb.n; i += 32 * 256) {
    jb.d[i] = isbf ? bf2f(((const u16*)jb.s)[i]) : ((const float*)jb.s)[i];
  }
}

// 4 bias-broadcast inits in one dispatch
struct IJobs { const float* b[4]; float* d[4]; int n[4]; int mask[4]; };
__global__ void k_init4(IJobs I) {
  const int j = blockIdx.y;
  const float* bb = I.b[j];
  float* dd = I.d[j];
  const int n = I.n[j], mask = I.mask[j];
  for (int i = blockIdx.x * 256 + threadIdx.x; i < n; i += gridDim.x * 256)
    dd[i] = bb[i & mask];
}

// Pack staged fp32 recurrent weights into the round-8 per-thread f16-pair
// layout consumed by k_rec (thread (r=tid>>2, kq=tid&3) owns rows r+128j x
// k-chunk kq):  dst[tid*64 + j*16 + kk] = pack(W[r+128j][kq*32+2kk], ..+1).
// Optional second source s2 -> element-wise sum (decoder Wih+Whh).
struct PJobs { const float* s[7]; const float* s2[7]; u32* d[7]; };
__global__ void k_pack(PJobs P) {
  const float* src = P.s[blockIdx.y];
  const float* src2 = P.s2[blockIdx.y];
  u32* dst = P.d[blockIdx.y];
  const int i = blockIdx.x * 256 + threadIdx.x;   // 0..32767
  const int tid = i >> 6, rem = i & 63;
  const int j = rem >> 4, kk = rem & 15;
  const int r = tid >> 2, kq = tid & 3;
  const int row = r + 128 * j, col = kq * 32 + 2 * kk;
  float v0 = src[row * 128 + col];
  float v1 = src[row * 128 + col + 1];
  if (src2) { v0 += src2[row * 128 + col]; v1 += src2[row * 128 + col + 1]; }
  H2U v;
  v.h.x = (_Float16)v0;
  v.h.y = (_Float16)v1;
  dst[i] = v.u;
}

// C[M,N] (+)= A[M,K] @ W[N,K]^T (+bias). 32-wide K staging, 16 B/lane loads.
__launch_bounds__(256)
__global__ void k_gemm(const float* __restrict__ A, int lda,
                       const void* __restrict__ Wv, int ldw,
                       const float* __restrict__ bias,
                       float* __restrict__ C, int ldc,
                       int K, int actA, int atom, int wfollow,
                       const int* __restrict__ dflag)
{
  __shared__ float As[32][65];
  __shared__ float Ws[32][65];
  const int isbf = wfollow ? *dflag : 0;
  const int tid = threadIdx.x;
  const int tx = tid & 15, ty = tid >> 4;
  const int m0 = blockIdx.x * 64, n0 = blockIdx.y * 64;
  const int kc = K / gridDim.z;
  const int k0 = blockIdx.z * kc;
  const int lr = tid >> 2;
  const int lk = (tid & 3) << 3;
  float acc[4][4] = {{0.f}};
  const float* Ap   = A + (size_t)(m0 + lr) * lda + k0 + lk;
  const u16*   Wp16 = (const u16*)Wv   + (size_t)(n0 + lr) * ldw + k0 + lk;
  const float* Wp32 = (const float*)Wv + (size_t)(n0 + lr) * ldw + k0 + lk;
  for (int kk = 0; kk < kc; kk += 32) {
    float4 av0 = *(const float4*)(Ap + kk);
    float4 av1 = *(const float4*)(Ap + kk + 4);
    float wv[8];
    if (isbf) {
      const uint4 wu = *(const uint4*)(Wp16 + kk);
      wv[0]=bf2f(wu.x & 0xffffu); wv[1]=bf2f(wu.x >> 16);
      wv[2]=bf2f(wu.y & 0xffffu); wv[3]=bf2f(wu.y >> 16);
      wv[4]=bf2f(wu.z & 0xffffu); wv[5]=bf2f(wu.z >> 16);
      wv[6]=bf2f(wu.w & 0xffffu); wv[7]=bf2f(wu.w >> 16);
    } else {
      const float4 w0 = *(const float4*)(Wp32 + kk);
      const float4 w1 = *(const float4*)(Wp32 + kk + 4);
      wv[0]=w0.x; wv[1]=w0.y; wv[2]=w0.z; wv[3]=w0.w;
      wv[4]=w1.x; wv[5]=w1.y; wv[6]=w1.z; wv[7]=w1.w;
    }
    if (actA) {
      av0.x = tanhfast(av0.x); av0.y = tanhfast(av0.y);
      av0.z = tanhfast(av0.z); av0.w = tanhfast(av0.w);
      av1.x = tanhfast(av1.x); av1.y = tanhfast(av1.y);
      av1.z = tanhfast(av1.z); av1.w = tanhfast(av1.w);
    }
    __syncthreads();
    As[lk+0][lr] = av0.x; As[lk+1][lr] = av0.y;
    As[lk+2][lr] = av0.z; As[lk+3][lr] = av0.w;
    As[lk+4][lr] = av1.x; As[lk+5][lr] = av1.y;
    As[lk+6][lr] = av1.z; As[lk+7][lr] = av1.w;
    #pragma unroll
    for (int q = 0; q < 8; ++q) Ws[lk+q][lr] = wv[q];
    __syncthreads();
    #pragma unroll
    for (int k = 0; k < 32; ++k) {
      float a[4], w[4];
      #pragma unroll
      for (int i = 0; i < 4; ++i) a[i] = As[k][ty + 16*i];
      #pragma unroll
      for (int j = 0; j < 4; ++j) w[j] = Ws[k][tx + 16*j];
      #pragma unroll
      for (int i = 0; i < 4; ++i)
        #pragma unroll
        for (int j = 0; j < 4; ++j)
          acc[i][j] = fmaf(a[i], w[j], acc[i][j]);
    }
  }
  #pragma unroll
  for (int i = 0; i < 4; ++i) {
    const int m = m0 + ty + 16*i;
    #pragma unroll
    for (int j = 0; j < 4; ++j) {
      const int n = n0 + tx + 16*j;
      if (atom) atomicAdd(&C[(size_t)m*ldc + n], acc[i][j]);
      else {
        const float bv = bias ? bias[n] : 0.0f;
        C[(size_t)m*ldc + n] = acc[i][j] + bv;
      }
    }
  }
}

// Recurrence — exact round-8 structure (proven 67us, 0 conflicts) with ONE
// change: the 8 per-step DS-pipe reduce shuffles (ds_swizzle, 2-deep) are now
// DPP quad_perm VALU adds (qadd_xor1/2). Round-9 post-mortem: the step time is
// DS-pipe-issue-bound (~17 DS ops/thread/step); this cuts it to ~9.
//  - Z staged to LDS up-front; in-loop reads are DS.
//  - h history buffered in consumed zall rows, bulk-flushed after the loop.
//  - f16-packed resident weights (64 VGPRs) + v_dot2_f32_f16.
__launch_bounds__(512)
__attribute__((amdgpu_waves_per_eu(2, 2)))
__global__ void k_rec(const float* __restrict__ Zf, const float* __restrict__ Zb,
                      const u32* __restrict__ Wf, const u32* __restrict__ Wb,
                      float* __restrict__ HS, int hstride, int offF, int offB,
                      const float* __restrict__ h0, const float* __restrict__ c0,
                      int zmode, int zld, float* __restrict__ Cout)
{
  const int b = blockIdx.x & 63;
  const int dir = blockIdx.x >> 6;
  const float* Z = dir ? Zb : Zf;
  const u32* Wg = dir ? Wb : Wf;
  const int off = dir ? offB : offF;
  const int tid = threadIdx.x;
  const int r = tid >> 2, kq = tid & 3;

  __shared__ __align__(16) float zall[64*512];   // 128 KB: staged Z, then h-out rows
  __shared__ __align__(16) u32 hbuf[2][64];      // packed f16 h, double-buffered
  __shared__ float h0buf[128];

  // --- bulk stage Z into LDS (coalesced float4) ---
  if (!zmode) {
    #pragma unroll
    for (int q = 0; q < 16; ++q) {
      const int fid = tid + 512*q;
      const int s = fid >> 7, c4 = (fid & 127) << 2;
      *(float4*)&zall[s*512 + c4] = *(const float4*)&Z[((size_t)s*64 + b)*zld + c4];
    }
  }

  u32 wp[64];
  {
    const uint4* wr = (const uint4*)(Wg + (size_t)tid * 64);
    #pragma unroll
    for (int q = 0; q < 16; ++q) {
      const uint4 u = wr[q];
      wp[q*4+0]=u.x; wp[q*4+1]=u.y; wp[q*4+2]=u.z; wp[q*4+3]=u.w;
    }
  }
  #pragma unroll
  for (int q = 0; q < 64; ++q)
    asm volatile("" : "+v"(wp[q]));

  float creg = c0 ? c0[b*128 + r] : 0.0f;
  if (tid < 64) {
    H2U v;
    if (h0) {
      v.h.x = (_Float16)h0[b*128 + 2*tid];
      v.h.y = (_Float16)h0[b*128 + 2*tid + 1];
    } else {
      v.h.x = (_Float16)0.f; v.h.y = (_Float16)0.f;
    }
    hbuf[0][tid] = v.u;
  }
  float zcst[4] = {0.f,0.f,0.f,0.f};
  if (zmode) {
    #pragma unroll
    for (int j = 0; j < 4; ++j) zcst[j] = Z[r + 128*j];
  }
  __syncthreads();

  for (int t = 0; t < 64; ++t) {
    const int s = dir ? (63 - t) : t;
    float zc[4];
    if (zmode) {
      #pragma unroll
      for (int j = 0; j < 4; ++j) zc[j] = zcst[j];
    } else {
      #pragma unroll
      for (int j = 0; j < 4; ++j) zc[j] = zall[s*512 + r + 128*j];
    }
    u32 hh16[16];
    {
      const u32* hp = hbuf[t & 1];
      *(uint4*)&hh16[0]  = *(const uint4*)&hp[kq*16];
      *(uint4*)&hh16[4]  = *(const uint4*)&hp[kq*16 + 4];
      *(uint4*)&hh16[8]  = *(const uint4*)&hp[kq*16 + 8];
      *(uint4*)&hh16[12] = *(const uint4*)&hp[kq*16 + 12];
    }
    float a[4] = {0.f,0.f,0.f,0.f};
    #pragma unroll
    for (int j = 0; j < 4; ++j)
      #pragma unroll
      for (int i = 0; i < 16; ++i)
        a[j] = dot2acc(wp[j*16 + i], hh16[i], a[j]);
    // quad reduce on the VALU (DPP), not the DS pipe
    #pragma unroll
    for (int j = 0; j < 4; ++j) {
      a[j] = qadd_xor1(a[j]);
      a[j] = qadd_xor2(a[j]);
    }
    const float zi = a[0] + zc[0], zf2 = a[1] + zc[1];
    const float zg = a[2] + zc[2], zo = a[3] + zc[3];
    const float cc = sigf(zf2) * creg + sigf(zi) * tanhfast(zg);
    const float hh = sigf(zo) * tanhfast(cc);
    creg = cc;
    const float hn = __shfl_down(hh, 4, 64);
    if (kq == 0) {
      if (t == 0) h0buf[r] = hh;
      else        zall[(t-1)*512 + r] = hh;   // row t-1 consumed last step
      if (!(r & 1)) {
        H2U v; v.h.x = (_Float16)hh; v.h.y = (_Float16)hn;
        hbuf[(t+1) & 1][r >> 1] = v.u;
      }
    }
    __syncthreads();
  }

  // --- bulk flush h history to global (coalesced within rows) ---
  for (int i = tid; i < 8192; i += 512) {
    const int t = i >> 7, k = i & 127;
    const int s = dir ? (63 - t) : t;
    const float v = (t == 0) ? h0buf[k] : zall[(t-1)*512 + k];
    HS[((size_t)s*64 + b)*hstride + off + k] = v;
  }
  if (Cout != nullptr && kq == 0) Cout[b*128 + r] = creg;
}

// Attention, fully parallel over (b, t-slice).
#define TS 132
__launch_bounds__(256, 1)
__global__ void k_att(const float* __restrict__ enco, const float* __restrict__ encp,
                      const float* __restrict__ Hdec, const float* __restrict__ Hproj,
                      const float* __restrict__ attw, float* __restrict__ flat)
{
  const int b = blockIdx.x;
  const int t0 = blockIdx.y * 16;
  const int tid = threadIdx.x;
  __shared__ __align__(16) float ep[64*TS];
  __shared__ __align__(16) float en[64*TS];
  __shared__ __align__(16) float hp[16*TS];
  __shared__ float S[64*17];
  __shared__ float aw[64*17];
  __shared__ __align__(16) float awt[128];

  for (int i = tid; i < 8192; i += 256) {
    const int s = i >> 7, k = i & 127;
    const size_t g = ((size_t)s*64 + b)*128 + k;
    ep[s*TS + k] = encp[g];
    en[s*TS + k] = enco[g];
  }
  for (int i = tid; i < 2048; i += 256) {
    const int t = i >> 7, k = i & 127;
    const size_t g = ((size_t)(t0 + t)*64 + b)*128 + k;
    hp[t*TS + k] = Hproj[g];
    flat[(size_t)b*16384 + (t0 + t)*256 + k] = Hdec[g];
  }
  if (tid < 128) awt[tid] = attw[tid];
  __syncthreads();

  {
    const int t = tid & 15, sg = tid >> 4;
    #pragma unroll
    for (int i = 0; i < 4; ++i) {
      const int s = sg*4 + i;
      float acc = 0.f;
      #pragma unroll 8
      for (int k = 0; k < 128; k += 4) {
        const float4 h4 = *(const float4*)&hp[t*TS + k];
        const float4 e4 = *(const float4*)&ep[s*TS + k];
        const float4 w4 = *(const float4*)&awt[k];
        acc = fmaf(w4.x, tanhfast(h4.x + e4.x), acc);
        acc = fmaf(w4.y, tanhfast(h4.y + e4.y), acc);
        acc = fmaf(w4.z, tanhfast(h4.z + e4.z), acc);
        acc = fmaf(w4.w, tanhfast(h4.w + e4.w), acc);
      }
      S[s*17 + t] = acc;
    }
  }
  __syncthreads();
  if (tid < 16) {
    const int t = tid;
    float m = -1e30f;
    for (int s = 0; s < 64; ++s) m = fmaxf(m, S[s*17 + t]);
    float sum = 0.f;
    for (int s = 0; s < 64; ++s) {
      const float e = __expf(S[s*17 + t] - m);
      aw[s*17 + t] = e;
      sum += e;
    }
    const float inv = 1.0f / sum;
    for (int s = 0; s < 64; ++s) aw[s*17 + t] *= inv;
  }
  __syncthreads();
  {
    const int t = tid >> 4, kg = tid & 15;
    float c0a[8] = {0,0,0,0,0,0,0,0};
    for (int s = 0; s < 64; ++s) {
      const float a = aw[s*17 + t];
      const float4 e0 = *(const float4*)&en[s*TS + kg*8];
      const float4 e1 = *(const float4*)&en[s*TS + kg*8 + 4];
      c0a[0] = fmaf(a, e0.x, c0a[0]);
      c0a[1] = fmaf(a, e0.y, c0a[1]);
      c0a[2] = fmaf(a, e0.z, c0a[2]);
      c0a[3] = fmaf(a, e0.w, c0a[3]);
      c0a[4] = fmaf(a, e1.x, c0a[4]);
      c0a[5] = fmaf(a, e1.y, c0a[5]);
      c0a[6] = fmaf(a, e1.z, c0a[6]);
      c0a[7] = fmaf(a, e1.w, c0a[7]);
    }
    float4 o0 = {c0a[0], c0a[1], c0a[2], c0a[3]};
    float4 o1 = {c0a[4], c0a[5], c0a[6], c0a[7]};
    float* dst = &flat[(size_t)b*16384 + (t0 + t)*256 + 128 + kg*8];
    *(float4*)dst = o0;
    *(float4*)(dst + 4) = o1;
  }
}

__global__ void k_head(const float* __restrict__ a4, const float* __restrict__ outW,
                       const float* __restrict__ outb, void* __restrict__ out,
                       const int* __restrict__ dflag)
{
  const int b = threadIdx.x;
  float acc = outb[0];
  #pragma unroll 8
  for (int k = 0; k < 128; ++k)
    acc = fmaf(outW[k], tanhfast(a4[b*128 + k]), acc);
  if (*dflag) ((u16*)out)[b] = f2bf(acc);
  else        ((float*)out)[b] = acc;
}

extern "C" void kernel_launch(void* const* d_in, const int* in_sizes, int n_in,
                              void* d_out, int out_size, void* d_ws, size_t ws_size,
                              hipStream_t stream)
{
  (void)in_sizes; (void)n_in; (void)out_size; (void)ws_size;

  float* p = (float*)d_ws;
  int*   flagp = (int*)p;    p += 64;
  float* x0    = p; p += 64*64*64;
  float* cl1Wih = p; p += 512*64;
  float* cl1Whh = p; p += 512*128;
  float* cl1b   = p; p += 512;
  float* c2Wih  = p; p += 1024*128;
  float* c2bias = p; p += 1024;
  float* c2fWhh = p; p += 512*128;
  float* c2bWhh = p; p += 512*128;
  float* c3Wih  = p; p += 1024*256;
  float* c3bias = p; p += 1024;
  float* c3fWhh = p; p += 512*128;
  float* c3bWhh = p; p += 512*128;
  float* ceWih  = p; p += 512*256;
  float* ceWhh  = p; p += 512*128;
  float* ceb    = p; p += 512;
  float* cdWih  = p; p += 512*128;
  float* cdWhh  = p; p += 512*128;
  float* cdb    = p; p += 512;
  float* cattW  = p; p += 128*128;
  float* cattw  = p; p += 128;
  float* cW1b   = p; p += 1024;
  float* cW2b   = p; p += 512;
  float* cW3b   = p; p += 256;
  float* cW4b   = p; p += 128;
  float* coW    = p; p += 128;
  float* cob    = p; p += 16;
  u32* wpL1 = (u32*)p; p += 32768;
  u32* wp2f = (u32*)p; p += 32768;
  u32* wp2b = (u32*)p; p += 32768;
  u32* wp3f = (u32*)p; p += 32768;
  u32* wp3b = (u32*)p; p += 32768;
  u32* wpE  = (u32*)p; p += 32768;
  u32* wpD  = (u32*)p; p += 32768;
  float* Zf   = p; p += 4096*512;
  float* Z2   = p; p += 4096*1024;
  float* h1   = p; p += 4096*128;
  float* x2   = p; p += 4096*256;
  float* x3   = p; p += 4096*256;
  float* enco = p; p += 4096*128;   // enco and Hdec contiguous (merged proj A)
  float* Hdec = p; p += 4096*128;
  float* encp = p; p += 4096*128;   // encp and Hprj contiguous (merged proj C)
  float* Hprj = p; p += 4096*128;
  float* ec   = p; p += 64*128;
  float* flat = p; p += 64*16384;
  float* a1   = p; p += 64*1024;
  float* a2   = p; p += 64*512;
  float* a3   = p; p += 64*256;
  float* a4   = p; p += 64*128;

  k_detect<<<1, 256, 0, stream>>>((const u32*)d_in[2], flagp);

  Jobs J;
  int nj = 0;
  auto add = [&](const void* s, float* d, int n) { J.j[nj].s = s; J.j[nj].d = d; J.j[nj].n = n; ++nj; };
  add(d_in[0],  x0,     64*64*64);
  add(d_in[1],  cl1Wih, 512*64);
  add(d_in[2],  cl1Whh, 512*128);
  add(d_in[3],  cl1b,   512);
  add(d_in[4],  c2Wih,            512*128);
  add(d_in[7],  c2Wih + 512*128,  512*128);
  add(d_in[6],  c2bias,       512);
  add(d_in[9],  c2bias + 512, 512);
  add(d_in[5],  c2fWhh, 512*128);
  add(d_in[8],  c2bWhh, 512*128);
  add(d_in[10], c3Wih,            512*256);
  add(d_in[13], c3Wih + 512*256,  512*256);
  add(d_in[12], c3bias,       512);
  add(d_in[15], c3bias + 512, 512);
  add(d_in[11], c3fWhh, 512*128);
  add(d_in[14], c3bWhh, 512*128);
  add(d_in[16], ceWih,  512*256);
  add(d_in[17], ceWhh,  512*128);
  add(d_in[18], ceb,    512);
  add(d_in[19], cdWih,  512*128);
  add(d_in[20], cdWhh,  512*128);
  add(d_in[21], cdb,    512);
  add(d_in[22], cattW,  128*128);
  add(d_in[23], cattw,  128);
  add(d_in[25], cW1b,   1024);
  add(d_in[27], cW2b,   512);
  add(d_in[29], cW3b,   256);
  add(d_in[31], cW4b,   128);
  add(d_in[32], coW,    128);
  add(d_in[33], cob,    1);
  k_cvt_all<<<dim3(32, nj), 256, 0, stream>>>(J, flagp);

  // pack all recurrent weight matrices into round-8 f16-pair layout;
  // dec entry sums Wih+Whh in-pack (xin == h_prev in the reference recurrence)
  PJobs P;
  for (int i = 0; i < 7; ++i) P.s2[i] = nullptr;
  P.s[0] = cl1Whh; P.d[0] = wpL1;
  P.s[1] = c2fWhh; P.d[1] = wp2f;
  P.s[2] = c2bWhh; P.d[2] = wp2b;
  P.s[3] = c3fWhh; P.d[3] = wp3f;
  P.s[4] = c3bWhh; P.d[4] = wp3b;
  P.s[5] = ceWhh;  P.d[5] = wpE;
  P.s[6] = cdWih;  P.s2[6] = cdWhh; P.d[6] = wpD;
  k_pack<<<dim3(128, 7), 256, 0, stream>>>(P);

  // lstm1
  k_gemm<<<dim3(64,8,1), 256, 0, stream>>>(x0, 64, cl1Wih, 64, cl1b, Zf, 512, 64, 0, 0, 0, flagp);
  k_rec<<<64, 512, 0, stream>>>(Zf, Zf, wpL1, wpL1, h1, 128, 0, 0, nullptr, nullptr, 0, 512, nullptr);

  // biLSTM 2 (f+b input GEMM merged: N=1024, shared A)
  k_gemm<<<dim3(64,16,1), 256, 0, stream>>>(h1, 128, c2Wih, 128, c2bias, Z2, 1024, 128, 0, 0, 0, flagp);
  k_rec<<<128, 512, 0, stream>>>(Z2, Z2 + 512, wp2f, wp2b, x2, 256, 0, 128, nullptr, nullptr, 0, 1024, nullptr);

  // biLSTM 3 (merged)
  k_gemm<<<dim3(64,16,1), 256, 0, stream>>>(x2, 256, c3Wih, 256, c3bias, Z2, 1024, 256, 0, 0, 0, flagp);
  k_rec<<<128, 512, 0, stream>>>(Z2, Z2 + 512, wp3f, wp3b, x3, 256, 0, 128, nullptr, nullptr, 0, 1024, nullptr);

  // encoder
  k_gemm<<<dim3(64,8,1), 256, 0, stream>>>(x3, 256, ceWih, 256, ceb, Zf, 512, 256, 0, 0, 0, flagp);
  k_rec<<<64, 512, 0, stream>>>(Zf, Zf, wpE, wpE, enco, 128, 0, 0, nullptr, nullptr, 0, 512, ec);

  // decoder recurrence (attention-independent): h0 = enco[63], c0 = ec, Z = bias
  k_rec<<<64, 512, 0, stream>>>(cdb, cdb, wpD, wpD, Hdec, 128, 0, 0,
                                enco + (size_t)63*64*128, ec, 1, 512, nullptr);

  // merged projection: [enco;Hdec] @ attW^T -> [encp;Hprj]  (M=8192)
  k_gemm<<<dim3(128,2,1), 256, 0, stream>>>(enco, 128, cattW, 128, nullptr, encp, 128, 128, 0, 0, 0, flagp);

  // attention (parallel over 64 b x 4 t-slices) -> flat [64, 16384]
  k_att<<<dim3(64,4), 256, 0, stream>>>(enco, encp, Hdec, Hprj, cattw, flat);

  // MLP: all bias-inits in one dispatch, then split-K atomic GEMMs
  IJobs I;
  I.b[0]=cW1b; I.d[0]=a1; I.n[0]=64*1024; I.mask[0]=1023;
  I.b[1]=cW2b; I.d[1]=a2; I.n[1]=64*512;  I.mask[1]=511;
  I.b[2]=cW3b; I.d[2]=a3; I.n[2]=64*256;  I.mask[2]=255;
  I.b[3]=cW4b; I.d[3]=a4; I.n[3]=64*128;  I.mask[3]=127;
  k_init4<<<dim3(64, 4), 256, 0, stream>>>(I);
  k_gemm<<<dim3(1,16,64), 256, 0, stream>>>(flat, 16384, d_in[24], 16384, nullptr, a1, 1024, 16384, 0, 1, 1, flagp);
  k_gemm<<<dim3(1,8,16), 256, 0, stream>>>(a1, 1024, d_in[26], 1024, nullptr, a2, 512, 1024, 1, 1, 1, flagp);
  k_gemm<<<dim3(1,4,8), 256, 0, stream>>>(a2, 512, d_in[28], 512, nullptr, a3, 256, 512, 1, 1, 1, flagp);
  k_gemm<<<dim3(1,2,4), 256, 0, stream>>>(a3, 256, d_in[30], 256, nullptr, a4, 128, 256, 1, 1, 1, flagp);

  k_head<<<1, 64, 0, stream>>>(a4, coW, cob, d_out, flagp);
}